// Round 9
// baseline (1299.433 us; speedup 1.0000x reference)
//
#include <hip/hip_runtime.h>
#include <float.h>

#define NS 1536
#define DD 64
#define RING 8

// ws layout (float elements)
static const size_t OFF_A  = 0;                          // A = h_sat + b1: [1536][64]
static const size_t OFF_C2 = 98304;                      // C2 = h_uav transposed [16][1536][4]
static const size_t OFF_L  = 196608;                     // logits [1536][1536]
static const size_t OFF_AS = 196608 + (size_t)NS * NS;   // int assign [1536]
// top_idx (ushort, 1536*256 = 786432 B) ALIASES the A/C2 region (dead after kB).

// ---------------- Kernel A: first-layer projections ----------------
__global__ __launch_bounds__(64) void kA(const float* __restrict__ sat,
                                         const float* __restrict__ uav,
                                         const float* __restrict__ W1,
                                         const float* __restrict__ b1,
                                         float* __restrict__ A,
                                         float* __restrict__ C2) {
    const int row = blockIdx.x;
    const int d = threadIdx.x;
    float accA = b1[d];
    float accC = 0.f;
    const float* __restrict__ satr = sat + row * DD;
    const float* __restrict__ uavr = uav + row * DD;
#pragma unroll 8
    for (int k = 0; k < DD; ++k) {
        accA = fmaf(satr[k], W1[k * DD + d], accA);
        accC = fmaf(uavr[k], W1[(DD + k) * DD + d], accC);
    }
    A[row * DD + d] = accA;
    C2[((size_t)(d >> 2) * NS + row) * 4 + (d & 3)] = accC;
}

// ---------------- Kernel B: all-pairs logits ----------------
__global__ __launch_bounds__(256) void kB(const float* __restrict__ A,
                                          const float* __restrict__ C2,
                                          const float* __restrict__ W2,
                                          const float* __restrict__ b2,
                                          const float* __restrict__ W3,
                                          float* __restrict__ L) {
    const int lane = threadIdx.x & 63;
    const int wave = threadIdx.x >> 6;
    const int i = __builtin_amdgcn_readfirstlane(blockIdx.x * 4 + wave);
    const int jbase = blockIdx.y * 256;
    const float* __restrict__ Ar = A + (size_t)i * DD;

    float u[4][32];
#pragma unroll
    for (int o = 0; o < 32; ++o) {
        const float b = b2[o];
        u[0][o] = b; u[1][o] = b; u[2][o] = b; u[3][o] = b;
    }

    const float4* __restrict__ C2v = (const float4*)C2;

    for (int d4 = 0; d4 < 16; ++d4) {
        float c[4][4];
#pragma unroll
        for (int p = 0; p < 4; ++p) {
            const float4 t = C2v[(size_t)d4 * NS + jbase + p * 64 + lane];
            c[p][0] = t.x; c[p][1] = t.y; c[p][2] = t.z; c[p][3] = t.w;
        }
#pragma unroll
        for (int dd = 0; dd < 4; ++dd) {
            const float a = Ar[d4 * 4 + dd];
            const float v0 = fmaxf(a + c[0][dd], 0.f);
            const float v1 = fmaxf(a + c[1][dd], 0.f);
            const float v2 = fmaxf(a + c[2][dd], 0.f);
            const float v3 = fmaxf(a + c[3][dd], 0.f);
            const float* __restrict__ w2r = W2 + (d4 * 4 + dd) * 32;
#pragma unroll
            for (int o = 0; o < 32; ++o) {
                const float w = w2r[o];
                u[0][o] = fmaf(v0, w, u[0][o]);
                u[1][o] = fmaf(v1, w, u[1][o]);
                u[2][o] = fmaf(v2, w, u[2][o]);
                u[3][o] = fmaf(v3, w, u[3][o]);
            }
        }
    }

#pragma unroll
    for (int p = 0; p < 4; ++p) {
        float acc = 0.f;
#pragma unroll
        for (int o = 0; o < 32; ++o)
            acc = fmaf(fmaxf(u[p][o], 0.f), W3[o], acc);
        L[(size_t)i * NS + jbase + p * 64 + lane] = acc;
    }
}

// ---------------- Kernel C: per-row sorted top-256 via 16-bit radix ----------------
// Swizzled layout: rank r lives at top[row*256 + (r&63)*4 + (r>>6)] so kD's
// uint2-per-lane read gives lane l ranks {l, l+64, l+128, l+192}.
__global__ __launch_bounds__(256) void kC(const float* __restrict__ L,
                                          unsigned short* __restrict__ top) {
    __shared__ int hist[256];
    __shared__ int suff[256];
    __shared__ float cv[1024];
    __shared__ int ci[1024];
    __shared__ int s_cnt, s_B0, s_base, s_B1;
    const int t = threadIdx.x;
    const int row = blockIdx.x;
    const float* __restrict__ Lr = L + (size_t)row * NS;

    top[row * 256 + t] = 0xFFFFu;   // sentinel (degenerate rows -> kD fallback)

    hist[t] = 0;
    if (t == 0) s_cnt = 0;
    __syncthreads();

    unsigned ub[6]; float fv[6];
#pragma unroll
    for (int k = 0; k < 6; ++k) {
        const float x = Lr[t + 256 * k];
        fv[k] = x;
        unsigned b = __float_as_uint(x);
        b = (b & 0x80000000u) ? ~b : (b | 0x80000000u);
        ub[k] = b;
        atomicAdd(&hist[b >> 24], 1);
    }
    __syncthreads();

    suff[t] = hist[t];
    __syncthreads();
    for (int off = 1; off < 256; off <<= 1) {
        const int v = (t + off < 256) ? suff[t + off] : 0;
        __syncthreads();
        suff[t] += v;
        __syncthreads();
    }
    if (suff[t] >= 256 && (t == 255 || suff[t + 1] < 256)) {
        s_B0 = t;
        s_base = (t == 255) ? 0 : suff[t + 1];
    }
    __syncthreads();
    const unsigned B0 = (unsigned)s_B0;
    const int base = s_base;

    hist[t] = 0;
    __syncthreads();
#pragma unroll
    for (int k = 0; k < 6; ++k)
        if ((ub[k] >> 24) == B0) atomicAdd(&hist[(ub[k] >> 16) & 255], 1);
    __syncthreads();
    suff[t] = hist[t];
    __syncthreads();
    for (int off = 1; off < 256; off <<= 1) {
        const int v = (t + off < 256) ? suff[t + off] : 0;
        __syncthreads();
        suff[t] += v;
        __syncthreads();
    }
    const int need = 256 - base;
    if (suff[t] >= need && (t == 255 || suff[t + 1] < need)) s_B1 = t;
    __syncthreads();
    const unsigned B1 = (unsigned)s_B1;
    const int m = base + suff[B1];
    if (m > 1024) return;

#pragma unroll
    for (int k = 0; k < 6; ++k) {
        const unsigned hi = ub[k] >> 24;
        const unsigned mid = (ub[k] >> 16) & 255u;
        if (hi > B0 || (hi == B0 && mid >= B1)) {
            const int pos = atomicAdd(&s_cnt, 1);
            cv[pos] = fv[k];
            ci[pos] = t + 256 * k;
        }
    }
    __syncthreads();

    for (int e = t; e < m; e += 256) {
        const float v = cv[e]; const int id = ci[e];
        int r = 0;
        for (int s2 = 0; s2 < m; ++s2) {
            const float vs = cv[s2];
            if (vs > v || (vs == v && ci[s2] < id)) ++r;
        }
        if (r < 256) top[row * 256 + (r & 63) * 4 + (r >> 6)] = (unsigned short)id;
    }
}

// Wave-wide max of a u32 via DPP (pure VALU, ~4-8cy/stage vs ~60cy/bpermute).
// bound_ctrl=true fills invalid source lanes with 0 -> 0 must be a safe
// identity (all our keys are > 0). Lane 63 holds the wave max afterwards.
__device__ __forceinline__ unsigned wave_max_u32_dpp(unsigned x) {
    unsigned t;
    t = (unsigned)__builtin_amdgcn_update_dpp(0, (int)x, 0x111, 0xF, 0xF, true); // row_shr:1
    x = x > t ? x : t;
    t = (unsigned)__builtin_amdgcn_update_dpp(0, (int)x, 0x112, 0xF, 0xF, true); // row_shr:2
    x = x > t ? x : t;
    t = (unsigned)__builtin_amdgcn_update_dpp(0, (int)x, 0x114, 0xF, 0xF, true); // row_shr:4
    x = x > t ? x : t;
    t = (unsigned)__builtin_amdgcn_update_dpp(0, (int)x, 0x118, 0xF, 0xF, true); // row_shr:8
    x = x > t ? x : t;
    t = (unsigned)__builtin_amdgcn_update_dpp(0, (int)x, 0x142, 0xF, 0xF, true); // row_bcast:15
    x = x > t ? x : t;
    t = (unsigned)__builtin_amdgcn_update_dpp(0, (int)x, 0x143, 0xF, 0xF, true); // row_bcast:31
    x = x > t ? x : t;
    return x;
}

// ---------------- Kernel D: greedy with producer/consumer waves --------------
// Wave 0 (consumer): round-6 ballot fast path; fallback reads the FULL row
//   from an LDS ring (6 x ds_read_b128 ~200cy) + packed used_b mask + 24
//   predicated compares + DPP argmax. No global latency on the serial chain.
// Wave 1 (producer): streams L rows into the 8-slot ring. Row values don't
//   depend on greedy decisions -> its ~600cy/row global latency runs fully
//   parallel to the consumer.
// Protocol: producer writes row r only when cons >= r-7 (slot free; consumer
//   publishes cons=i+1 after finishing row i -> slot i&7 can't be overwritten
//   early). Consumer fallback waits ready >= i+1 (published after lgkmcnt(0);
//   DS in-order per wave -> flag implies data). Poll is BOUNDED with a
//   direct-global safety valve -> correctness never depends on the sync.
__global__ __launch_bounds__(128) void kD(const float* __restrict__ L,
                                          const unsigned short* __restrict__ top,
                                          int* __restrict__ assign) {
    __shared__ int used_s[NS];             // word flags (ballot-path reads)
    __shared__ unsigned used_b[NS / 32];   // packed bits (fallback reads)
    __shared__ int assign_s[NS];
    __shared__ float ring[RING][NS];       // 48KB row ring
    __shared__ int ctl[2];                 // [0]=cons progress, [1]=ready
    const int tid = threadIdx.x;
    for (int k = tid; k < NS; k += 128) used_s[k] = 0;
    if (tid < NS / 32) used_b[tid] = 0u;
    if (tid < 2) ctl[tid] = 0;
    __syncthreads();

    volatile int* vctl = ctl;

    if (tid >= 64) {
        // ================= producer wave =================
        const int plane = tid - 64;
        for (int r = 0; r < NS; ++r) {
            while (vctl[0] < r - (RING - 1)) __builtin_amdgcn_s_sleep(1);
            const float4* __restrict__ Lr4 =
                (const float4*)(L + (size_t)r * NS);
            float4 v[6];
#pragma unroll
            for (int m = 0; m < 6; ++m) v[m] = Lr4[plane + 64 * m];
            float4* __restrict__ S4 = (float4*)&ring[r & (RING - 1)][0];
#pragma unroll
            for (int m = 0; m < 6; ++m) S4[plane + 64 * m] = v[m];
            asm volatile("s_waitcnt lgkmcnt(0)");
            if (plane == 0) vctl[1] = r + 1;
        }
        return;
    }

    // ================= consumer wave =================
    const int lane = tid;
    const uint2* __restrict__ T = (const uint2*)top;   // T[row*64 + lane]

    uint2 buf[16];           // rows g..g+15
#pragma unroll
    for (int k = 0; k < 16; ++k) buf[k] = T[k * 64 + lane];

    int f0 = 0, f1 = 0, f2 = 0, f3 = 0;   // row-0 flags: nothing used yet
    int jprev = -1;

    for (int g = 0; g < NS; g += 8) {
        // issue T loads for rows g+16..g+23 (consumed 2 groups from now)
        uint2 nb[8];
#pragma unroll
        for (int k = 0; k < 8; ++k) {
            int r = g + 16 + k;
            r = (r < NS) ? r : (NS - 1);
            nb[k] = T[r * 64 + lane];
        }

#pragma unroll
        for (int q = 0; q < 8; ++q) {
            const int i = g + q;

            // prefetch used-flags for row i+1 (candidates resident in buf[q+1])
            const uint2 pn = buf[q + 1];
            const int n0 = (int)(pn.x & 0xFFFFu), n1 = (int)(pn.x >> 16);
            const int n2 = (int)(pn.y & 0xFFFFu), n3 = (int)(pn.y >> 16);
            const int g0 = used_s[n0 < NS ? n0 : 0];
            const int g1 = used_s[n1 < NS ? n1 : 0];
            const int g2 = used_s[n2 < NS ? n2 : 0];
            const int g3 = used_s[n3 < NS ? n3 : 0];

            const uint2 pc = buf[q];
            const int c0 = (int)(pc.x & 0xFFFFu), c1 = (int)(pc.x >> 16);
            const int c2 = (int)(pc.y & 0xFFFFu), c3 = (int)(pc.y >> 16);
            const bool a0 = (c0 < NS) && (f0 == 0) && (c0 != jprev);
            const bool a1 = (c1 < NS) && (f1 == 0) && (c1 != jprev);
            const bool a2 = (c2 < NS) && (f2 == 0) && (c2 != jprev);
            const bool a3 = (c3 < NS) && (f3 == 0) && (c3 != jprev);
            const unsigned long long b0 = __ballot(a0);
            const unsigned long long b1 = __ballot(a1);
            const unsigned long long b2 = __ballot(a2);
            const unsigned long long b3 = __ballot(a3);

            int j;
            if (b0)      j = __builtin_amdgcn_readlane(c0, __ffsll(b0) - 1);
            else if (b1) j = __builtin_amdgcn_readlane(c1, __ffsll(b1) - 1);
            else if (b2) j = __builtin_amdgcn_readlane(c2, __ffsll(b2) - 1);
            else if (b3) j = __builtin_amdgcn_readlane(c3, __ffsll(b3) - 1);
            else {
                // ---- fallback: masked argmax over full row i from LDS ring ----
                int sp = 0; bool staged = true;
                while (vctl[1] < i + 1) {
                    __builtin_amdgcn_s_sleep(1);
                    if (++sp > 2048) { staged = false; break; }
                }
                float4 v4[6];
                if (staged) {
                    const float4* __restrict__ S4 =
                        (const float4*)&ring[i & (RING - 1)][0];
#pragma unroll
                    for (int m = 0; m < 6; ++m) v4[m] = S4[lane + 64 * m];
                } else {
                    const float4* __restrict__ Lr4 =
                        (const float4*)(L + (size_t)i * NS);
#pragma unroll
                    for (int m = 0; m < 6; ++m) v4[m] = Lr4[lane + 64 * m];
                }
                unsigned w[6];
#pragma unroll
                for (int m = 0; m < 6; ++m) w[m] = used_b[(lane >> 3) + 8 * m];

                const int bsh = 4 * (lane & 7);
                float bv = -FLT_MAX; int bi = NS;
#pragma unroll
                for (int m = 0; m < 6; ++m) {
                    const int colb = 4 * lane + 256 * m;
                    const float vs[4] = {v4[m].x, v4[m].y, v4[m].z, v4[m].w};
#pragma unroll
                    for (int sub = 0; sub < 4; ++sub) {
                        const int col = colb + sub;
                        const bool free_ = ((w[m] >> (bsh + sub)) & 1u) == 0u;
                        const float v = vs[sub];
                        if (free_ && (v > bv || (v == bv && col < bi))) {
                            bv = v; bi = col;
                        }
                    }
                }
                // ---- DPP wave argmax (val desc, idx asc tiebreak) ----
                unsigned key = __float_as_uint(bv);
                key = (key & 0x80000000u) ? ~key : (key | 0x80000000u);
                const unsigned wk = wave_max_u32_dpp(key);
                const unsigned maxk =
                    (unsigned)__builtin_amdgcn_readlane((int)wk, 63);
                unsigned cand = (key == maxk) ? (unsigned)(NS - bi) : 0u;
                const unsigned wc = wave_max_u32_dpp(cand);
                const unsigned mc =
                    (unsigned)__builtin_amdgcn_readlane((int)wc, 63);
                j = NS - (int)mc;
            }
            if (lane == 0) {
                used_s[j] = 1;
                used_b[j >> 5] |= (1u << (j & 31));
                assign_s[i] = j;
                vctl[0] = i + 1;          // release ring slot i&7
            }
            jprev = j;
            f0 = g0; f1 = g1; f2 = g2; f3 = g3;
        }

        // rotate: waits only for loads issued ~8 rows ago (fully landed)
#pragma unroll
        for (int k = 0; k < 8; ++k) buf[k] = buf[k + 8];
#pragma unroll
        for (int k = 0; k < 8; ++k) buf[k + 8] = nb[k];
    }

    for (int k = lane; k < NS; k += 64) assign[k] = assign_s[k];
}

// ---------------- Kernel E: emit [1536][2][64] output ----------------
__global__ __launch_bounds__(128) void kE(const float* __restrict__ sat,
                                          const float* __restrict__ uav,
                                          const int* __restrict__ assign,
                                          float* __restrict__ out) {
    const int i = blockIdx.x;
    const int t = threadIdx.x;
    if (t < 64) out[(size_t)i * 128 + t] = sat[(size_t)i * DD + t];
    else        out[(size_t)i * 128 + t] = uav[(size_t)assign[i] * DD + (t - 64)];
}

extern "C" void kernel_launch(void* const* d_in, const int* in_sizes, int n_in,
                              void* d_out, int out_size, void* d_ws, size_t ws_size,
                              hipStream_t stream) {
    const float* sat = (const float*)d_in[0];
    const float* uav = (const float*)d_in[1];
    const float* W1  = (const float*)d_in[2];
    const float* b1  = (const float*)d_in[3];
    const float* W2  = (const float*)d_in[4];
    const float* b2  = (const float*)d_in[5];
    const float* W3  = (const float*)d_in[6];
    // d_in[7] = b3: sigmoid(x+b3) monotone in x — argmax unchanged.

    float* ws = (float*)d_ws;
    float* A   = ws + OFF_A;
    float* C2  = ws + OFF_C2;
    float* L   = ws + OFF_L;
    int* assign = (int*)(ws + OFF_AS);
    unsigned short* top = (unsigned short*)(ws + OFF_A);  // aliases A/C2 (dead after kB)

    hipLaunchKernelGGL(kA, dim3(NS), dim3(64), 0, stream, sat, uav, W1, b1, A, C2);
    hipLaunchKernelGGL(kB, dim3(NS / 4, NS / 256), dim3(256), 0, stream,
                       A, C2, W2, b2, W3, L);
    hipLaunchKernelGGL(kC, dim3(NS), dim3(256), 0, stream, L, top);
    hipLaunchKernelGGL(kD, dim3(1), dim3(128), 0, stream, L, top, assign);
    hipLaunchKernelGGL(kE, dim3(NS), dim3(128), 0, stream, sat, uav, assign,
                       (float*)d_out);
}

// Round 10
// 1049.692 us; speedup vs baseline: 1.2379x; 1.2379x over previous
//
#include <hip/hip_runtime.h>
#include <float.h>

#define NS 1536
#define DD 64
#define RING 8

// ws layout (float elements)
static const size_t OFF_A  = 0;                          // A = h_sat + b1: [1536][64]
static const size_t OFF_C2 = 98304;                      // C2 = h_uav transposed [16][1536][4]
static const size_t OFF_L  = 196608;                     // logits [1536][1536]
static const size_t OFF_AS = 196608 + (size_t)NS * NS;   // int assign [1536]
// top_idx (ushort, 1536*256 = 786432 B) ALIASES the A/C2 region (dead after kB).

// ---------------- Kernel A: first-layer projections ----------------
__global__ __launch_bounds__(64) void kA(const float* __restrict__ sat,
                                         const float* __restrict__ uav,
                                         const float* __restrict__ W1,
                                         const float* __restrict__ b1,
                                         float* __restrict__ A,
                                         float* __restrict__ C2) {
    const int row = blockIdx.x;
    const int d = threadIdx.x;
    float accA = b1[d];
    float accC = 0.f;
    const float* __restrict__ satr = sat + row * DD;
    const float* __restrict__ uavr = uav + row * DD;
#pragma unroll 8
    for (int k = 0; k < DD; ++k) {
        accA = fmaf(satr[k], W1[k * DD + d], accA);
        accC = fmaf(uavr[k], W1[(DD + k) * DD + d], accC);
    }
    A[row * DD + d] = accA;
    C2[((size_t)(d >> 2) * NS + row) * 4 + (d & 3)] = accC;
}

// ---------------- Kernel B: all-pairs logits ----------------
__global__ __launch_bounds__(256) void kB(const float* __restrict__ A,
                                          const float* __restrict__ C2,
                                          const float* __restrict__ W2,
                                          const float* __restrict__ b2,
                                          const float* __restrict__ W3,
                                          float* __restrict__ L) {
    const int lane = threadIdx.x & 63;
    const int wave = threadIdx.x >> 6;
    const int i = __builtin_amdgcn_readfirstlane(blockIdx.x * 4 + wave);
    const int jbase = blockIdx.y * 256;
    const float* __restrict__ Ar = A + (size_t)i * DD;

    float u[4][32];
#pragma unroll
    for (int o = 0; o < 32; ++o) {
        const float b = b2[o];
        u[0][o] = b; u[1][o] = b; u[2][o] = b; u[3][o] = b;
    }

    const float4* __restrict__ C2v = (const float4*)C2;

    for (int d4 = 0; d4 < 16; ++d4) {
        float c[4][4];
#pragma unroll
        for (int p = 0; p < 4; ++p) {
            const float4 t = C2v[(size_t)d4 * NS + jbase + p * 64 + lane];
            c[p][0] = t.x; c[p][1] = t.y; c[p][2] = t.z; c[p][3] = t.w;
        }
#pragma unroll
        for (int dd = 0; dd < 4; ++dd) {
            const float a = Ar[d4 * 4 + dd];
            const float v0 = fmaxf(a + c[0][dd], 0.f);
            const float v1 = fmaxf(a + c[1][dd], 0.f);
            const float v2 = fmaxf(a + c[2][dd], 0.f);
            const float v3 = fmaxf(a + c[3][dd], 0.f);
            const float* __restrict__ w2r = W2 + (d4 * 4 + dd) * 32;
#pragma unroll
            for (int o = 0; o < 32; ++o) {
                const float w = w2r[o];
                u[0][o] = fmaf(v0, w, u[0][o]);
                u[1][o] = fmaf(v1, w, u[1][o]);
                u[2][o] = fmaf(v2, w, u[2][o]);
                u[3][o] = fmaf(v3, w, u[3][o]);
            }
        }
    }

#pragma unroll
    for (int p = 0; p < 4; ++p) {
        float acc = 0.f;
#pragma unroll
        for (int o = 0; o < 32; ++o)
            acc = fmaf(fmaxf(u[p][o], 0.f), W3[o], acc);
        L[(size_t)i * NS + jbase + p * 64 + lane] = acc;
    }
}

// ---------------- Kernel C: per-row sorted top-256 via 16-bit radix ----------------
// Swizzled layout: rank r lives at top[row*256 + (r&63)*4 + (r>>6)] so kD's
// uint2-per-lane read gives lane l ranks {l, l+64, l+128, l+192}.
__global__ __launch_bounds__(256) void kC(const float* __restrict__ L,
                                          unsigned short* __restrict__ top) {
    __shared__ int hist[256];
    __shared__ int suff[256];
    __shared__ float cv[1024];
    __shared__ int ci[1024];
    __shared__ int s_cnt, s_B0, s_base, s_B1;
    const int t = threadIdx.x;
    const int row = blockIdx.x;
    const float* __restrict__ Lr = L + (size_t)row * NS;

    top[row * 256 + t] = 0xFFFFu;   // sentinel (degenerate rows -> kD fallback)

    hist[t] = 0;
    if (t == 0) s_cnt = 0;
    __syncthreads();

    unsigned ub[6]; float fv[6];
#pragma unroll
    for (int k = 0; k < 6; ++k) {
        const float x = Lr[t + 256 * k];
        fv[k] = x;
        unsigned b = __float_as_uint(x);
        b = (b & 0x80000000u) ? ~b : (b | 0x80000000u);
        ub[k] = b;
        atomicAdd(&hist[b >> 24], 1);
    }
    __syncthreads();

    suff[t] = hist[t];
    __syncthreads();
    for (int off = 1; off < 256; off <<= 1) {
        const int v = (t + off < 256) ? suff[t + off] : 0;
        __syncthreads();
        suff[t] += v;
        __syncthreads();
    }
    if (suff[t] >= 256 && (t == 255 || suff[t + 1] < 256)) {
        s_B0 = t;
        s_base = (t == 255) ? 0 : suff[t + 1];
    }
    __syncthreads();
    const unsigned B0 = (unsigned)s_B0;
    const int base = s_base;

    hist[t] = 0;
    __syncthreads();
#pragma unroll
    for (int k = 0; k < 6; ++k)
        if ((ub[k] >> 24) == B0) atomicAdd(&hist[(ub[k] >> 16) & 255], 1);
    __syncthreads();
    suff[t] = hist[t];
    __syncthreads();
    for (int off = 1; off < 256; off <<= 1) {
        const int v = (t + off < 256) ? suff[t + off] : 0;
        __syncthreads();
        suff[t] += v;
        __syncthreads();
    }
    const int need = 256 - base;
    if (suff[t] >= need && (t == 255 || suff[t + 1] < need)) s_B1 = t;
    __syncthreads();
    const unsigned B1 = (unsigned)s_B1;
    const int m = base + suff[B1];
    if (m > 1024) return;

#pragma unroll
    for (int k = 0; k < 6; ++k) {
        const unsigned hi = ub[k] >> 24;
        const unsigned mid = (ub[k] >> 16) & 255u;
        if (hi > B0 || (hi == B0 && mid >= B1)) {
            const int pos = atomicAdd(&s_cnt, 1);
            cv[pos] = fv[k];
            ci[pos] = t + 256 * k;
        }
    }
    __syncthreads();

    for (int e = t; e < m; e += 256) {
        const float v = cv[e]; const int id = ci[e];
        int r = 0;
        for (int s2 = 0; s2 < m; ++s2) {
            const float vs = cv[s2];
            if (vs > v || (vs == v && ci[s2] < id)) ++r;
        }
        if (r < 256) top[row * 256 + (r & 63) * 4 + (r >> 6)] = (unsigned short)id;
    }
}

// Wave-wide max of a u32 via DPP (pure VALU, ~4-8cy/stage vs ~60cy/bpermute).
// bound_ctrl=true fills invalid source lanes with 0 -> 0 must be a safe
// identity (all our keys are > 0). Lane 63 holds the wave max afterwards.
__device__ __forceinline__ unsigned wave_max_u32_dpp(unsigned x) {
    unsigned t;
    t = (unsigned)__builtin_amdgcn_update_dpp(0, (int)x, 0x111, 0xF, 0xF, true); // row_shr:1
    x = x > t ? x : t;
    t = (unsigned)__builtin_amdgcn_update_dpp(0, (int)x, 0x112, 0xF, 0xF, true); // row_shr:2
    x = x > t ? x : t;
    t = (unsigned)__builtin_amdgcn_update_dpp(0, (int)x, 0x114, 0xF, 0xF, true); // row_shr:4
    x = x > t ? x : t;
    t = (unsigned)__builtin_amdgcn_update_dpp(0, (int)x, 0x118, 0xF, 0xF, true); // row_shr:8
    x = x > t ? x : t;
    t = (unsigned)__builtin_amdgcn_update_dpp(0, (int)x, 0x142, 0xF, 0xF, true); // row_bcast:15
    x = x > t ? x : t;
    t = (unsigned)__builtin_amdgcn_update_dpp(0, (int)x, 0x143, 0xF, 0xF, true); // row_bcast:31
    x = x > t ? x : t;
    return x;
}

// ---------------- Kernel D: greedy with 2 pipelined producer waves ----------
// Round-9 fix: kD was producer-throughput-limited (708cy/row = un-pipelined
// single producer). Now 2 producer waves (even/odd rows) x 2-deep software
// pipeline -> aggregate ~150cy/row << consumer rate -> ring pinned 8-ahead,
// consumer fallback wait ~ one LDS flag read. Producers SKIP rows the
// consumer already passed (vctl[0] > r: consumer never reads that slot).
// Consumer fallback: 6 ds_read_b128 from ring + packed used_b mask + u64
// (key,col) pack + depth-5 tree max + 2-phase DPP. Global valve kept.
__global__ __launch_bounds__(192) void kD(const float* __restrict__ L,
                                          const unsigned short* __restrict__ top,
                                          int* __restrict__ assign) {
    __shared__ int used_s[NS];             // word flags (ballot-path reads)
    __shared__ unsigned used_b[NS / 32];   // packed bits (fallback reads)
    __shared__ int assign_s[NS];
    __shared__ float ring[RING][NS];       // 48KB row ring
    __shared__ int ctl[4];                 // [0]=cons, [1]=ready_even, [2]=ready_odd
    const int tid = threadIdx.x;
    for (int k = tid; k < NS; k += 192) used_s[k] = 0;
    if (tid < NS / 32) used_b[tid] = 0u;
    if (tid < 4) ctl[tid] = 0;
    __syncthreads();

    volatile int* vctl = ctl;

    if (tid >= 64) {
        // ================= producer waves (even rows / odd rows) =============
        const int plane = tid & 63;
        const int p0 = (tid >= 128) ? 1 : 0;   // row parity this wave owns
        volatile int* rdy = &ctl[1 + p0];
        float4 va[6], vb[6];
        {
            const float4* __restrict__ Lr4 = (const float4*)(L + (size_t)p0 * NS);
#pragma unroll
            for (int m = 0; m < 6; ++m) va[m] = Lr4[plane + 64 * m];
        }
        {
            const float4* __restrict__ Lr4 = (const float4*)(L + (size_t)(p0 + 2) * NS);
#pragma unroll
            for (int m = 0; m < 6; ++m) vb[m] = Lr4[plane + 64 * m];
        }
        for (int r = p0; r < NS; r += 4) {
            // ---- row r (va) ----
            while (vctl[0] < r - (RING - 1)) __builtin_amdgcn_s_sleep(1);
            if (vctl[0] <= r) {          // consumer not past r -> store needed
                float4* __restrict__ S4 = (float4*)&ring[r & (RING - 1)][0];
#pragma unroll
                for (int m = 0; m < 6; ++m) S4[plane + 64 * m] = va[m];
                asm volatile("s_waitcnt lgkmcnt(0)");
            }
            if (plane == 0) *rdy = (r >> 1) + 1;
            if (r + 4 < NS) {
                const float4* __restrict__ Lr4 =
                    (const float4*)(L + (size_t)(r + 4) * NS);
#pragma unroll
                for (int m = 0; m < 6; ++m) va[m] = Lr4[plane + 64 * m];
            }
            // ---- row r+2 (vb) ----
            const int r2 = r + 2;
            while (vctl[0] < r2 - (RING - 1)) __builtin_amdgcn_s_sleep(1);
            if (vctl[0] <= r2) {
                float4* __restrict__ S4 = (float4*)&ring[r2 & (RING - 1)][0];
#pragma unroll
                for (int m = 0; m < 6; ++m) S4[plane + 64 * m] = vb[m];
                asm volatile("s_waitcnt lgkmcnt(0)");
            }
            if (plane == 0) *rdy = (r2 >> 1) + 1;
            if (r2 + 4 < NS) {
                const float4* __restrict__ Lr4 =
                    (const float4*)(L + (size_t)(r2 + 4) * NS);
#pragma unroll
                for (int m = 0; m < 6; ++m) vb[m] = Lr4[plane + 64 * m];
            }
        }
        return;
    }

    // ================= consumer wave (round-6 skeleton) =================
    const int lane = tid;
    const uint2* __restrict__ T = (const uint2*)top;   // T[row*64 + lane]

    uint2 buf[16];           // rows g..g+15
#pragma unroll
    for (int k = 0; k < 16; ++k) buf[k] = T[k * 64 + lane];

    int f0 = 0, f1 = 0, f2 = 0, f3 = 0;   // row-0 flags: nothing used yet
    int jprev = -1;

    for (int g = 0; g < NS; g += 8) {
        // issue T loads for rows g+16..g+23 (consumed 2 groups from now)
        uint2 nb[8];
#pragma unroll
        for (int k = 0; k < 8; ++k) {
            int r = g + 16 + k;
            r = (r < NS) ? r : (NS - 1);
            nb[k] = T[r * 64 + lane];
        }

#pragma unroll
        for (int q = 0; q < 8; ++q) {
            const int i = g + q;

            // prefetch used-flags for row i+1 (candidates resident in buf[q+1])
            const uint2 pn = buf[q + 1];
            const int n0 = (int)(pn.x & 0xFFFFu), n1 = (int)(pn.x >> 16);
            const int n2 = (int)(pn.y & 0xFFFFu), n3 = (int)(pn.y >> 16);
            const int g0 = used_s[n0 < NS ? n0 : 0];
            const int g1 = used_s[n1 < NS ? n1 : 0];
            const int g2 = used_s[n2 < NS ? n2 : 0];
            const int g3 = used_s[n3 < NS ? n3 : 0];

            const uint2 pc = buf[q];
            const int c0 = (int)(pc.x & 0xFFFFu), c1 = (int)(pc.x >> 16);
            const int c2 = (int)(pc.y & 0xFFFFu), c3 = (int)(pc.y >> 16);
            const bool a0 = (c0 < NS) && (f0 == 0) && (c0 != jprev);
            const bool a1 = (c1 < NS) && (f1 == 0) && (c1 != jprev);
            const bool a2 = (c2 < NS) && (f2 == 0) && (c2 != jprev);
            const bool a3 = (c3 < NS) && (f3 == 0) && (c3 != jprev);
            const unsigned long long b0 = __ballot(a0);
            const unsigned long long b1 = __ballot(a1);
            const unsigned long long b2 = __ballot(a2);
            const unsigned long long b3 = __ballot(a3);

            int j;
            if (b0)      j = __builtin_amdgcn_readlane(c0, __ffsll(b0) - 1);
            else if (b1) j = __builtin_amdgcn_readlane(c1, __ffsll(b1) - 1);
            else if (b2) j = __builtin_amdgcn_readlane(c2, __ffsll(b2) - 1);
            else if (b3) j = __builtin_amdgcn_readlane(c3, __ffsll(b3) - 1);
            else {
                // ---- fallback: masked argmax over full row i ----
                // mask first (depends only on commits <= i-1, already done)
                unsigned w[6];
#pragma unroll
                for (int m = 0; m < 6; ++m) w[m] = used_b[(lane >> 3) + 8 * m];

                volatile int* rdy = &ctl[1 + (i & 1)];
                int sp = 0; bool staged = true;
                while (*rdy <= (i >> 1)) {
                    __builtin_amdgcn_s_sleep(1);
                    if (++sp > 4096) { staged = false; break; }
                }
                float4 v4[6];
                if (staged) {
                    const float4* __restrict__ S4 =
                        (const float4*)&ring[i & (RING - 1)][0];
#pragma unroll
                    for (int m = 0; m < 6; ++m) v4[m] = S4[lane + 64 * m];
                } else {
                    const float4* __restrict__ Lr4 =
                        (const float4*)(L + (size_t)i * NS);
#pragma unroll
                    for (int m = 0; m < 6; ++m) v4[m] = Lr4[lane + 64 * m];
                }

                // pack (sortable key, 4096-col) into u64; used -> 0
                const int bsh = 4 * (lane & 7);
                unsigned long long kk[24];
#pragma unroll
                for (int m = 0; m < 6; ++m) {
                    const int colb = 4 * lane + 256 * m;
                    const float vs[4] = {v4[m].x, v4[m].y, v4[m].z, v4[m].w};
#pragma unroll
                    for (int sub = 0; sub < 4; ++sub) {
                        unsigned b = __float_as_uint(vs[sub]);
                        unsigned key = (b & 0x80000000u) ? ~b : (b | 0x80000000u);
                        const bool used = ((w[m] >> (bsh + sub)) & 1u) != 0u;
                        const unsigned lowp = (unsigned)(4096 - (colb + sub));
                        kk[m * 4 + sub] = used ? 0ULL
                            : ((((unsigned long long)key) << 32) | lowp);
                    }
                }
                // depth-5 tree max (vs 24-deep serial chain: round-8 lesson)
#pragma unroll
                for (int s2 = 0; s2 < 12; ++s2)
                    kk[s2] = kk[s2] > kk[s2 + 12] ? kk[s2] : kk[s2 + 12];
#pragma unroll
                for (int s2 = 0; s2 < 6; ++s2)
                    kk[s2] = kk[s2] > kk[s2 + 6] ? kk[s2] : kk[s2 + 6];
#pragma unroll
                for (int s2 = 0; s2 < 3; ++s2)
                    kk[s2] = kk[s2] > kk[s2 + 3] ? kk[s2] : kk[s2 + 3];
                kk[0] = kk[0] > kk[1] ? kk[0] : kk[1];
                kk[0] = kk[0] > kk[2] ? kk[0] : kk[2];

                unsigned key = (unsigned)(kk[0] >> 32);
                unsigned lowp = (unsigned)kk[0];
                const unsigned wk = wave_max_u32_dpp(key);
                const unsigned maxk =
                    (unsigned)__builtin_amdgcn_readlane((int)wk, 63);
                unsigned cand = (key == maxk) ? lowp : 0u;
                const unsigned wc = wave_max_u32_dpp(cand);
                const unsigned mc =
                    (unsigned)__builtin_amdgcn_readlane((int)wc, 63);
                j = 4096 - (int)mc;
            }
            if (lane == 0) {
                used_s[j] = 1;
                used_b[j >> 5] |= (1u << (j & 31));
                assign_s[i] = j;
                vctl[0] = i + 1;          // release ring slot i&7
            }
            jprev = j;
            f0 = g0; f1 = g1; f2 = g2; f3 = g3;
        }

        // rotate: waits only for loads issued ~8 rows ago (fully landed)
#pragma unroll
        for (int k = 0; k < 8; ++k) buf[k] = buf[k + 8];
#pragma unroll
        for (int k = 0; k < 8; ++k) buf[k + 8] = nb[k];
    }

    for (int k = lane; k < NS; k += 64) assign[k] = assign_s[k];
}

// ---------------- Kernel E: emit [1536][2][64] output ----------------
__global__ __launch_bounds__(128) void kE(const float* __restrict__ sat,
                                          const float* __restrict__ uav,
                                          const int* __restrict__ assign,
                                          float* __restrict__ out) {
    const int i = blockIdx.x;
    const int t = threadIdx.x;
    if (t < 64) out[(size_t)i * 128 + t] = sat[(size_t)i * DD + t];
    else        out[(size_t)i * 128 + t] = uav[(size_t)assign[i] * DD + (t - 64)];
}

extern "C" void kernel_launch(void* const* d_in, const int* in_sizes, int n_in,
                              void* d_out, int out_size, void* d_ws, size_t ws_size,
                              hipStream_t stream) {
    const float* sat = (const float*)d_in[0];
    const float* uav = (const float*)d_in[1];
    const float* W1  = (const float*)d_in[2];
    const float* b1  = (const float*)d_in[3];
    const float* W2  = (const float*)d_in[4];
    const float* b2  = (const float*)d_in[5];
    const float* W3  = (const float*)d_in[6];
    // d_in[7] = b3: sigmoid(x+b3) monotone in x — argmax unchanged.

    float* ws = (float*)d_ws;
    float* A   = ws + OFF_A;
    float* C2  = ws + OFF_C2;
    float* L   = ws + OFF_L;
    int* assign = (int*)(ws + OFF_AS);
    unsigned short* top = (unsigned short*)(ws + OFF_A);  // aliases A/C2 (dead after kB)

    hipLaunchKernelGGL(kA, dim3(NS), dim3(64), 0, stream, sat, uav, W1, b1, A, C2);
    hipLaunchKernelGGL(kB, dim3(NS / 4, NS / 256), dim3(256), 0, stream,
                       A, C2, W2, b2, W3, L);
    hipLaunchKernelGGL(kC, dim3(NS), dim3(256), 0, stream, L, top);
    hipLaunchKernelGGL(kD, dim3(1), dim3(192), 0, stream, L, top, assign);
    hipLaunchKernelGGL(kE, dim3(NS), dim3(128), 0, stream, sat, uav, assign,
                       (float*)d_out);
}

// Round 11
// 1015.082 us; speedup vs baseline: 1.2801x; 1.0341x over previous
//
#include <hip/hip_runtime.h>
#include <float.h>

#define NS 1536
#define DD 64

// ws layout (float elements)
static const size_t OFF_A  = 0;                          // A = h_sat + b1: [1536][64]
static const size_t OFF_C2 = 98304;                      // C2 = h_uav transposed [16][1536][4]
static const size_t OFF_L  = 196608;                     // logits [1536][1536]
static const size_t OFF_AS = 196608 + (size_t)NS * NS;   // int assign [1536]

// ---------------- Kernel A: first-layer projections ----------------
__global__ __launch_bounds__(64) void kA(const float* __restrict__ sat,
                                         const float* __restrict__ uav,
                                         const float* __restrict__ W1,
                                         const float* __restrict__ b1,
                                         float* __restrict__ A,
                                         float* __restrict__ C2) {
    const int row = blockIdx.x;
    const int d = threadIdx.x;
    float accA = b1[d];
    float accC = 0.f;
    const float* __restrict__ satr = sat + row * DD;
    const float* __restrict__ uavr = uav + row * DD;
#pragma unroll 8
    for (int k = 0; k < DD; ++k) {
        accA = fmaf(satr[k], W1[k * DD + d], accA);
        accC = fmaf(uavr[k], W1[(DD + k) * DD + d], accC);
    }
    A[row * DD + d] = accA;
    C2[((size_t)(d >> 2) * NS + row) * 4 + (d & 3)] = accC;
}

// ---------------- Kernel B: all-pairs logits ----------------
__global__ __launch_bounds__(256) void kB(const float* __restrict__ A,
                                          const float* __restrict__ C2,
                                          const float* __restrict__ W2,
                                          const float* __restrict__ b2,
                                          const float* __restrict__ W3,
                                          float* __restrict__ L) {
    const int lane = threadIdx.x & 63;
    const int wave = threadIdx.x >> 6;
    const int i = __builtin_amdgcn_readfirstlane(blockIdx.x * 4 + wave);
    const int jbase = blockIdx.y * 256;
    const float* __restrict__ Ar = A + (size_t)i * DD;

    float u[4][32];
#pragma unroll
    for (int o = 0; o < 32; ++o) {
        const float b = b2[o];
        u[0][o] = b; u[1][o] = b; u[2][o] = b; u[3][o] = b;
    }

    const float4* __restrict__ C2v = (const float4*)C2;

    for (int d4 = 0; d4 < 16; ++d4) {
        float c[4][4];
#pragma unroll
        for (int p = 0; p < 4; ++p) {
            const float4 t = C2v[(size_t)d4 * NS + jbase + p * 64 + lane];
            c[p][0] = t.x; c[p][1] = t.y; c[p][2] = t.z; c[p][3] = t.w;
        }
#pragma unroll
        for (int dd = 0; dd < 4; ++dd) {
            const float a = Ar[d4 * 4 + dd];
            const float v0 = fmaxf(a + c[0][dd], 0.f);
            const float v1 = fmaxf(a + c[1][dd], 0.f);
            const float v2 = fmaxf(a + c[2][dd], 0.f);
            const float v3 = fmaxf(a + c[3][dd], 0.f);
            const float* __restrict__ w2r = W2 + (d4 * 4 + dd) * 32;
#pragma unroll
            for (int o = 0; o < 32; ++o) {
                const float w = w2r[o];
                u[0][o] = fmaf(v0, w, u[0][o]);
                u[1][o] = fmaf(v1, w, u[1][o]);
                u[2][o] = fmaf(v2, w, u[2][o]);
                u[3][o] = fmaf(v3, w, u[3][o]);
            }
        }
    }

#pragma unroll
    for (int p = 0; p < 4; ++p) {
        float acc = 0.f;
#pragma unroll
        for (int o = 0; o < 32; ++o)
            acc = fmaf(fmaxf(u[p][o], 0.f), W3[o], acc);
        L[(size_t)i * NS + jbase + p * 64 + lane] = acc;
    }
}

// Wave-wide max of a u32 via DPP (pure VALU). bound_ctrl=true fills invalid
// source lanes with 0 -> 0 must be a safe identity (all keys used are > 0).
// Lane 63 holds the wave max afterwards.
__device__ __forceinline__ unsigned wave_max_u32_dpp(unsigned x) {
    unsigned t;
    t = (unsigned)__builtin_amdgcn_update_dpp(0, (int)x, 0x111, 0xF, 0xF, true); // row_shr:1
    x = x > t ? x : t;
    t = (unsigned)__builtin_amdgcn_update_dpp(0, (int)x, 0x112, 0xF, 0xF, true); // row_shr:2
    x = x > t ? x : t;
    t = (unsigned)__builtin_amdgcn_update_dpp(0, (int)x, 0x114, 0xF, 0xF, true); // row_shr:4
    x = x > t ? x : t;
    t = (unsigned)__builtin_amdgcn_update_dpp(0, (int)x, 0x118, 0xF, 0xF, true); // row_shr:8
    x = x > t ? x : t;
    t = (unsigned)__builtin_amdgcn_update_dpp(0, (int)x, 0x142, 0xF, 0xF, true); // row_bcast:15
    x = x > t ? x : t;
    t = (unsigned)__builtin_amdgcn_update_dpp(0, (int)x, 0x143, 0xF, 0xF, true); // row_bcast:31
    x = x > t ? x : t;
    return x;
}

// ---------------- Kernel D: dense greedy, single wave, pure-VALU chain ------
// One uniform path: exact masked argmax over the full row EVERY row.
//  - values: 4-deep register ring rv[4][6] (float4), slot refilled with row
//    i+4 immediately after extraction (reuse distance 4 rows ~1600cy >> HBM
//    latency -> no vmcnt stall; compile-time slot via unroll-4).
//  - mask: per-lane 24-bit 'dead' register (lane owns cols 4*lane+256m+sub);
//    owner-lane update = 3 VALU ops per commit. NO LDS on the serial chain.
//  - reduce: cndmask->-FLT_MAX, fmaxf tree (max3-fusible), per-lane min-col
//    match, then the proven 2-phase DPP cross-lane argmax.
// No kC / top / used_s / ballot machinery; no sync protocols (r9/r10 lesson);
// no speculation state (r5/r7 lesson). ~450-530cy/row deterministic.
__global__ __launch_bounds__(64) void kD(const float* __restrict__ L,
                                         int* __restrict__ assign) {
    __shared__ int assign_s[NS];
    const int lane = threadIdx.x;

    const float4* __restrict__ L4 = (const float4*)L;  // row r: L4[r*384+lane+64m]

    float4 rv[4][6];
#pragma unroll
    for (int r = 0; r < 4; ++r)
#pragma unroll
        for (int m = 0; m < 6; ++m)
            rv[r][m] = L4[(size_t)r * 384 + lane + 64 * m];

    unsigned dead = 0u;   // bit (4m+sub) set <=> col 4*lane+256m+sub used

    for (int g = 0; g < NS; g += 4) {
#pragma unroll
        for (int q = 0; q < 4; ++q) {
            const int i = g + q;

            // ---- extract + mask (consumes rv[q]) ----
            float x[24];
#pragma unroll
            for (int m = 0; m < 6; ++m) {
                const float4 v4 = rv[q][m];
                x[4 * m + 0] = (dead & (1u << (4 * m + 0))) ? -FLT_MAX : v4.x;
                x[4 * m + 1] = (dead & (1u << (4 * m + 1))) ? -FLT_MAX : v4.y;
                x[4 * m + 2] = (dead & (1u << (4 * m + 2))) ? -FLT_MAX : v4.z;
                x[4 * m + 3] = (dead & (1u << (4 * m + 3))) ? -FLT_MAX : v4.w;
            }

            // ---- refill slot q with row i+4 (WAR-safe; hides issue under compute)
            {
                int r2 = i + 4; r2 = (r2 < NS) ? r2 : (NS - 1);
#pragma unroll
                for (int m = 0; m < 6; ++m)
                    rv[q][m] = L4[(size_t)r2 * 384 + lane + 64 * m];
            }

            // ---- per-lane max (tree; max3-fusible) ----
            float p[6];
#pragma unroll
            for (int m = 0; m < 6; ++m)
                p[m] = fmaxf(fmaxf(x[4 * m], x[4 * m + 1]),
                             fmaxf(x[4 * m + 2], x[4 * m + 3]));
            const float bv = fmaxf(fmaxf(fmaxf(p[0], p[1]), fmaxf(p[2], p[3])),
                                   fmaxf(p[4], p[5]));

            // ---- per-lane min col among x==bv ----
            int mm[6];
#pragma unroll
            for (int m = 0; m < 6; ++m) {
                const int c0 = 4 * lane + 256 * m;
                const int m0 = (x[4 * m + 0] == bv) ? (c0 + 0) : 4095;
                const int m1 = (x[4 * m + 1] == bv) ? (c0 + 1) : 4095;
                const int m2 = (x[4 * m + 2] == bv) ? (c0 + 2) : 4095;
                const int m3 = (x[4 * m + 3] == bv) ? (c0 + 3) : 4095;
                mm[m] = min(min(m0, m1), min(m2, m3));
            }
            const int ci = min(min(min(mm[0], mm[1]), min(mm[2], mm[3])),
                               min(mm[4], mm[5]));

            // ---- cross-lane argmax: 2-phase DPP (val desc, col asc) ----
            unsigned b = __float_as_uint(bv);
            unsigned key = (b & 0x80000000u) ? ~b : (b | 0x80000000u);
            const unsigned wk = wave_max_u32_dpp(key);
            const unsigned maxk = (unsigned)__builtin_amdgcn_readlane((int)wk, 63);
            unsigned cand = (key == maxk) ? (unsigned)(4096 - ci) : 0u;
            const unsigned wc = wave_max_u32_dpp(cand);
            const unsigned mc = (unsigned)__builtin_amdgcn_readlane((int)wc, 63);
            const int j = 4096 - (int)mc;

            // ---- commit: LDS store (off-chain) + owner-lane dead update ----
            if (lane == 0) assign_s[i] = j;
            const unsigned jb = 1u << ((((unsigned)j >> 8) << 2) + ((unsigned)j & 3u));
            if ((((unsigned)j >> 2) & 63u) == (unsigned)lane) dead |= jb;
        }
    }

    for (int k = lane; k < NS; k += 64) assign[k] = assign_s[k];
}

// ---------------- Kernel E: emit [1536][2][64] output ----------------
__global__ __launch_bounds__(128) void kE(const float* __restrict__ sat,
                                          const float* __restrict__ uav,
                                          const int* __restrict__ assign,
                                          float* __restrict__ out) {
    const int i = blockIdx.x;
    const int t = threadIdx.x;
    if (t < 64) out[(size_t)i * 128 + t] = sat[(size_t)i * DD + t];
    else        out[(size_t)i * 128 + t] = uav[(size_t)assign[i] * DD + (t - 64)];
}

extern "C" void kernel_launch(void* const* d_in, const int* in_sizes, int n_in,
                              void* d_out, int out_size, void* d_ws, size_t ws_size,
                              hipStream_t stream) {
    const float* sat = (const float*)d_in[0];
    const float* uav = (const float*)d_in[1];
    const float* W1  = (const float*)d_in[2];
    const float* b1  = (const float*)d_in[3];
    const float* W2  = (const float*)d_in[4];
    const float* b2  = (const float*)d_in[5];
    const float* W3  = (const float*)d_in[6];
    // d_in[7] = b3: sigmoid(x+b3) monotone in x — argmax unchanged.

    float* ws = (float*)d_ws;
    float* A   = ws + OFF_A;
    float* C2  = ws + OFF_C2;
    float* L   = ws + OFF_L;
    int* assign = (int*)(ws + OFF_AS);

    hipLaunchKernelGGL(kA, dim3(NS), dim3(64), 0, stream, sat, uav, W1, b1, A, C2);
    hipLaunchKernelGGL(kB, dim3(NS / 4, NS / 256), dim3(256), 0, stream,
                       A, C2, W2, b2, W3, L);
    hipLaunchKernelGGL(kD, dim3(1), dim3(64), 0, stream, L, assign);
    hipLaunchKernelGGL(kE, dim3(NS), dim3(128), 0, stream, sat, uav, assign,
                       (float*)d_out);
}